// Round 3
// baseline (295.220 us; speedup 1.0000x reference)
//
#include <hip/hip_runtime.h>

// GymNetwork: routed MLP, B=262144, D=128 -> F=80 -> 80 -> 80 -> A=18, G=8 games (idx sorted).
// I/O is FLOAT32 (per reference); compute is bf16 MFMA (threshold 6e-2 = 8*bf16_eps*max|ref|
// explicitly permits bf16 tensor-core compute). R2's NaN: f32 buffers read as bf16 -> NaN bit
// patterns from mantissa halves. Fix: f32 loads everywhere, convert to bf16 in registers/LDS.
//
// Structure: 128-row tile/block, 4 waves x 32 rows, mfma_f32_16x16x32_bf16, K padded 80->96
// with zero-B fragments; routed layers loop over the sorted tile's [g_lo,g_hi] with masked
// epilogue. h2 pad cols zeroed per-wave (NaN*0=NaN hazard on uninitialized LDS).

#define B_TOT   262144
#define DDIM    128
#define NGAMES  8
#define FDIM    80
#define ADIM    18
#define MT      128    // rows per block
#define SD      136    // LDS stride (shorts) for state tile: 272B rows -> 2-way (free) banks
#define SH      104    // LDS stride (shorts) for feature tiles: 208B rows -> 2-way (free) banks

typedef __attribute__((ext_vector_type(8))) short short8;
typedef __attribute__((ext_vector_type(4))) short short4v;
typedef __attribute__((ext_vector_type(4))) float floatx4;

static __device__ __forceinline__ unsigned short f2bf(float f) {
  union { float f; unsigned u; } v; v.f = f;
  unsigned r = v.u + 0x7fffu + ((v.u >> 16) & 1u);   // RNE
  return (unsigned short)(r >> 16);
}

// Load 8 consecutive f32 and pack to a bf16 short8 fragment.
static __device__ __forceinline__ short8 ld_frag_f32(const float* p) {
  floatx4 a = *(const floatx4*)p;
  floatx4 b = *(const floatx4*)(p + 4);
  short8 r;
  r[0] = (short)f2bf(a[0]); r[1] = (short)f2bf(a[1]);
  r[2] = (short)f2bf(a[2]); r[3] = (short)f2bf(a[3]);
  r[4] = (short)f2bf(b[0]); r[5] = (short)f2bf(b[1]);
  r[6] = (short)f2bf(b[2]); r[7] = (short)f2bf(b[3]);
  return r;
}

// Shared 80x80 layer: sOut[r][c] = relu(sIn[r][:] @ W^T + b), strides SH, K padded to 96.
// Each wave touches only its own 32 rows (no cross-wave barrier needed).
static __device__ __forceinline__ void mlp_layer(
    const unsigned short* sIn, unsigned short* sOut,
    const float* __restrict__ W, const float* __restrict__ bias,
    int rowbase, int l16, int quad)
{
  floatx4 acc[2][5];
#pragma unroll
  for (int rt = 0; rt < 2; ++rt)
#pragma unroll
    for (int ct = 0; ct < 5; ++ct) acc[rt][ct] = (floatx4){0.f, 0.f, 0.f, 0.f};
#pragma unroll
  for (int ks = 0; ks < 3; ++ks) {
    int k0 = ks * 32 + quad * 8;
    short8 a0 = *(const short8*)(sIn + (rowbase + l16) * SH + k0);
    short8 a1 = *(const short8*)(sIn + (rowbase + 16 + l16) * SH + k0);
    bool kv = (k0 < FDIM);   // k-chunks align to 8; chunk fully valid or fully pad
    short8 bf[5];
#pragma unroll
    for (int ct = 0; ct < 5; ++ct) {
      short8 z = {0, 0, 0, 0, 0, 0, 0, 0};
      bf[ct] = kv ? ld_frag_f32(W + (ct * 16 + l16) * FDIM + k0) : z;
    }
#pragma unroll
    for (int ct = 0; ct < 5; ++ct) {
      acc[0][ct] = __builtin_amdgcn_mfma_f32_16x16x32_bf16(a0, bf[ct], acc[0][ct], 0, 0, 0);
      acc[1][ct] = __builtin_amdgcn_mfma_f32_16x16x32_bf16(a1, bf[ct], acc[1][ct], 0, 0, 0);
    }
  }
#pragma unroll
  for (int rt = 0; rt < 2; ++rt)
#pragma unroll
    for (int ct = 0; ct < 5; ++ct) {
      int col = ct * 16 + l16;
      float bv = bias[col];
#pragma unroll
      for (int r = 0; r < 4; ++r) {
        int row = rowbase + rt * 16 + quad * 4 + r;   // C/D: col=lane&15, row=quad*4+reg
        float v = fmaxf(acc[rt][ct][r] + bv, 0.f);
        sOut[row * SH + col] = f2bf(v);
      }
    }
}

__global__ __launch_bounds__(256, 2) void gym_fused(
    const float* __restrict__ state, const int* __restrict__ idx,
    const float* __restrict__ W1, const float* __restrict__ b1,
    const float* __restrict__ W2, const float* __restrict__ b2,
    const float* __restrict__ W3, const float* __restrict__ b3,
    const float* __restrict__ W4, const float* __restrict__ b4,
    float* __restrict__ out)
{
  __shared__ __align__(16) unsigned short s_state[MT * SD];  // 34816 B; reused as h2 (stride SH)
  __shared__ __align__(16) unsigned short s_bufA[MT * SH];   // 26624 B; h1 then h3
  __shared__ int s_idx[MT];

  const int tid  = threadIdx.x;
  const int lane = tid & 63;
  const int wv   = tid >> 6;
  const int l16  = lane & 15;
  const int quad = lane >> 4;
  const int rowbase = wv * 32;                 // each wave owns 32 rows
  const size_t blk_row0 = (size_t)blockIdx.x * MT;
  const short8 zero8 = {0, 0, 0, 0, 0, 0, 0, 0};

  // ---- stage state tile: f32 global (coalesced float4) -> bf16 LDS; idx; zero h1 pads ----
  {
    const float* gsrc = state + blk_row0 * DDIM;
#pragma unroll
    for (int i = 0; i < 16; ++i) {
      int c = i * 256 + tid;                   // float4-chunk id 0..4095 (32 chunks per row)
      int r = c >> 5, cc = c & 31;
      floatx4 v = *(const floatx4*)(gsrc + c * 4);
      short4v s;
      s[0] = (short)f2bf(v[0]); s[1] = (short)f2bf(v[1]);
      s[2] = (short)f2bf(v[2]); s[3] = (short)f2bf(v[3]);
      *(short4v*)(s_state + r * SD + cc * 4) = s;
    }
  }
  if (tid < MT) s_idx[tid] = idx[blk_row0 + tid];
  {
    int r = tid >> 1, cc = tid & 1;
    *(short8*)(s_bufA + r * SH + 80 + cc * 8) = zero8;
  }
  __syncthreads();

  const int g_lo = s_idx[0];
  const int g_hi = s_idx[MT - 1];              // idx sorted -> games in tile = [g_lo, g_hi]

  // ---- layer 1 (routed): h1 = relu(state @ W1[g]^T + b1[g]) ----
  for (int g = g_lo; g <= g_hi; ++g) {
    floatx4 acc[2][5];
#pragma unroll
    for (int rt = 0; rt < 2; ++rt)
#pragma unroll
      for (int ct = 0; ct < 5; ++ct) acc[rt][ct] = (floatx4){0.f, 0.f, 0.f, 0.f};
    const float* w1g = W1 + g * (FDIM * DDIM);
#pragma unroll
    for (int ks = 0; ks < 4; ++ks) {
      int k0 = ks * 32 + quad * 8;
      short8 a0 = *(const short8*)(s_state + (rowbase + l16) * SD + k0);
      short8 a1 = *(const short8*)(s_state + (rowbase + 16 + l16) * SD + k0);
      short8 bf[5];
#pragma unroll
      for (int ct = 0; ct < 5; ++ct)
        bf[ct] = ld_frag_f32(w1g + (ct * 16 + l16) * DDIM + k0);
#pragma unroll
      for (int ct = 0; ct < 5; ++ct) {
        acc[0][ct] = __builtin_amdgcn_mfma_f32_16x16x32_bf16(a0, bf[ct], acc[0][ct], 0, 0, 0);
        acc[1][ct] = __builtin_amdgcn_mfma_f32_16x16x32_bf16(a1, bf[ct], acc[1][ct], 0, 0, 0);
      }
    }
#pragma unroll
    for (int rt = 0; rt < 2; ++rt)
#pragma unroll
      for (int ct = 0; ct < 5; ++ct) {
        int col = ct * 16 + l16;
        float bv = b1[g * FDIM + col];
#pragma unroll
        for (int r = 0; r < 4; ++r) {
          int row = rowbase + rt * 16 + quad * 4 + r;
          if (s_idx[row] == g) {
            float v = fmaxf(acc[rt][ct][r] + bv, 0.f);
            s_bufA[row * SH + col] = f2bf(v);
          }
        }
      }
  }
  // all waves done reading s_state as 'state' before anyone overwrites it with h2
  __syncthreads();

  unsigned short* s_h2 = s_state;              // reuse (stride SH)
  // Zero this wave's h2 pad cols 80..95 (uninitialized LDS; NaN*0=NaN through MFMA).
  {
    int r = rowbase + (lane >> 1), cc = lane & 1;
    *(short8*)(s_h2 + r * SH + 80 + cc * 8) = zero8;
  }

  // ---- layers 2,3 (shared) ----
  mlp_layer(s_bufA, s_h2,  W2, b2, rowbase, l16, quad);
  mlp_layer(s_h2,  s_bufA, W3, b3, rowbase, l16, quad);

  // ---- layer 4 (routed heads): q = h3 @ W4[g]^T + b4[g], f32 out ----
  for (int g = g_lo; g <= g_hi; ++g) {
    floatx4 acc[2][2];
#pragma unroll
    for (int rt = 0; rt < 2; ++rt)
#pragma unroll
      for (int ct = 0; ct < 2; ++ct) acc[rt][ct] = (floatx4){0.f, 0.f, 0.f, 0.f};
    const float* w4g = W4 + g * (ADIM * FDIM);
#pragma unroll
    for (int ks = 0; ks < 3; ++ks) {
      int k0 = ks * 32 + quad * 8;
      bool kv = (k0 < FDIM);
      short8 a0 = *(const short8*)(s_bufA + (rowbase + l16) * SH + k0);
      short8 a1 = *(const short8*)(s_bufA + (rowbase + 16 + l16) * SH + k0);
      short8 bf[2];
#pragma unroll
      for (int ct = 0; ct < 2; ++ct) {
        int n = ct * 16 + l16;
        bf[ct] = (kv && n < ADIM) ? ld_frag_f32(w4g + n * FDIM + k0) : zero8;
      }
#pragma unroll
      for (int ct = 0; ct < 2; ++ct) {
        acc[0][ct] = __builtin_amdgcn_mfma_f32_16x16x32_bf16(a0, bf[ct], acc[0][ct], 0, 0, 0);
        acc[1][ct] = __builtin_amdgcn_mfma_f32_16x16x32_bf16(a1, bf[ct], acc[1][ct], 0, 0, 0);
      }
    }
#pragma unroll
    for (int rt = 0; rt < 2; ++rt)
#pragma unroll
      for (int ct = 0; ct < 2; ++ct) {
        int col = ct * 16 + l16;
        if (col < ADIM) {
          float bv = b4[g * ADIM + col];
#pragma unroll
          for (int r = 0; r < 4; ++r) {
            int row = rowbase + rt * 16 + quad * 4 + r;
            if (s_idx[row] == g)
              out[(blk_row0 + row) * ADIM + col] = acc[rt][ct][r] + bv;
          }
        }
      }
  }
}

extern "C" void kernel_launch(void* const* d_in, const int* in_sizes, int n_in,
                              void* d_out, int out_size, void* d_ws, size_t ws_size,
                              hipStream_t stream) {
  const float* state = (const float*)d_in[0];
  const int*   idx   = (const int*)d_in[1];
  const float* W1    = (const float*)d_in[2];
  const float* b1    = (const float*)d_in[3];
  const float* W2    = (const float*)d_in[4];
  const float* b2    = (const float*)d_in[5];
  const float* W3    = (const float*)d_in[6];
  const float* b3    = (const float*)d_in[7];
  const float* W4    = (const float*)d_in[8];
  const float* b4    = (const float*)d_in[9];
  float*       out   = (float*)d_out;

  dim3 grid(B_TOT / MT);   // 2048 blocks
  dim3 block(256);
  gym_fused<<<grid, block, 0, stream>>>(state, idx, W1, b1, W2, b2, W3, b3, W4, b4, out);
}

// Round 4
// 266.210 us; speedup vs baseline: 1.1090x; 1.1090x over previous
//
#include <hip/hip_runtime.h>

// GymNetwork: routed MLP, B=262144, D=128 -> F=80 -> 80 -> 80 -> A=18, G=8 (idx sorted).
// f32 I/O, bf16 MFMA compute (threshold 6e-2 = 8*bf16_eps*max|ref|).
//
// R3 was latency-bound (HBM 7.6%, MFMA 4%, VALU 21%, occ 21%): 2 blocks/CU (LDS-capped)
// and per-wave f32 weight loads + f32->bf16 conversion in the K-loops.
// R4: (1) prologue kernel pre-converts weights to bf16 in d_ws, pre-padded with zeros
//     (W2/W3 -> 80x96, W4 -> 8x32x96) so B-fragments are single b128 loads, no branches;
//     (2) MT=64 (4 waves x 16 rows) -> ~31 KB LDS -> 5 blocks/CU (20 waves/CU).

#define B_TOT   262144
#define DDIM    128
#define NGAMES  8
#define FDIM    80
#define ADIM    18
#define MT      64     // rows per block
#define SD      136    // LDS stride (shorts) for state tile
#define SH      104    // LDS stride (shorts) for feature tiles
#define KP      96     // padded K for feature layers

// bf16 weight workspace layout (shorts)
#define W1O     0                       // [G][80][128]
#define W2O     81920                   // [80][96]  (k pads zeroed)
#define W3O     89600                   // [80][96]
#define W4O     97280                   // [G][32][96] (n,k pads zeroed)
#define WTOT    121856                  // shorts = 243712 bytes

typedef __attribute__((ext_vector_type(8))) short short8;
typedef __attribute__((ext_vector_type(4))) short short4v;
typedef __attribute__((ext_vector_type(4))) float floatx4;

static __device__ __forceinline__ unsigned short f2bf(float f) {
  union { float f; unsigned u; } v; v.f = f;
  unsigned r = v.u + 0x7fffu + ((v.u >> 16) & 1u);   // RNE
  return (unsigned short)(r >> 16);
}

// ---- prologue: f32 weights -> bf16 (padded) in ws ----
__global__ void convert_weights(const float* __restrict__ W1, const float* __restrict__ W2,
                                const float* __restrict__ W3, const float* __restrict__ W4,
                                unsigned short* __restrict__ ws) {
  int t = blockIdx.x * 256 + threadIdx.x;
  if (t < W2O) {                                   // W1: straight copy-convert
    ws[t] = f2bf(W1[t]);
  } else if (t < W3O) {                            // W2: 80x80 -> 80x96
    int i = t - W2O, n = i / KP, k = i - n * KP;
    ws[t] = (k < FDIM) ? f2bf(W2[n * FDIM + k]) : (unsigned short)0;
  } else if (t < W4O) {                            // W3
    int i = t - W3O, n = i / KP, k = i - n * KP;
    ws[t] = (k < FDIM) ? f2bf(W3[n * FDIM + k]) : (unsigned short)0;
  } else if (t < WTOT) {                           // W4: Gx18x80 -> Gx32x96
    int i = t - W4O, g = i / (32 * KP), r = i - g * (32 * KP);
    int n = r / KP, k = r - n * KP;
    ws[t] = (n < ADIM && k < FDIM) ? f2bf(W4[(g * ADIM + n) * FDIM + k]) : (unsigned short)0;
  }
}

// Shared 80x80 layer: sOut[r][:] = relu(sIn[r][:] @ W^T + b); strides SH; K padded to 96
// with zero LDS pads (A) and zero ws pads (B). Own-wave rows only.
static __device__ __forceinline__ void mlp_layer(
    const unsigned short* sIn, unsigned short* sOut,
    const unsigned short* __restrict__ Wbf, const float* __restrict__ bias,
    int rowbase, int l16, int quad)
{
  floatx4 acc[5];
#pragma unroll
  for (int ct = 0; ct < 5; ++ct) acc[ct] = (floatx4){0.f, 0.f, 0.f, 0.f};
#pragma unroll
  for (int ks = 0; ks < 3; ++ks) {
    int k0 = ks * 32 + quad * 8;
    short8 a = *(const short8*)(sIn + (rowbase + l16) * SH + k0);
    short8 bf[5];
#pragma unroll
    for (int ct = 0; ct < 5; ++ct)
      bf[ct] = *(const short8*)(Wbf + (ct * 16 + l16) * KP + k0);
#pragma unroll
    for (int ct = 0; ct < 5; ++ct)
      acc[ct] = __builtin_amdgcn_mfma_f32_16x16x32_bf16(a, bf[ct], acc[ct], 0, 0, 0);
  }
#pragma unroll
  for (int ct = 0; ct < 5; ++ct) {
    int col = ct * 16 + l16;
    float bv = bias[col];
#pragma unroll
    for (int r = 0; r < 4; ++r) {
      int row = rowbase + quad * 4 + r;            // C/D: col=lane&15, row=quad*4+reg
      float v = fmaxf(acc[ct][r] + bv, 0.f);
      sOut[row * SH + col] = f2bf(v);
    }
  }
}

__global__ __launch_bounds__(256, 5) void gym_fused(
    const float* __restrict__ state, const int* __restrict__ idx,
    const unsigned short* __restrict__ wbf,
    const float* __restrict__ b1, const float* __restrict__ b2,
    const float* __restrict__ b3, const float* __restrict__ b4,
    float* __restrict__ out)
{
  __shared__ __align__(16) unsigned short s_state[MT * SD];  // 17408 B; reused as h2 (stride SH)
  __shared__ __align__(16) unsigned short s_bufA[MT * SH];   // 13312 B; h1 then h3
  __shared__ int s_idx[MT];

  const int tid  = threadIdx.x;
  const int lane = tid & 63;
  const int wv   = tid >> 6;
  const int l16  = lane & 15;
  const int quad = lane >> 4;
  const int rowbase = wv * 16;                 // each wave owns 16 rows
  const size_t blk_row0 = (size_t)blockIdx.x * MT;
  const short8 zero8 = {0, 0, 0, 0, 0, 0, 0, 0};

  // ---- stage state tile: f32 global (coalesced float4) -> bf16 LDS; idx; zero h1 pads ----
  {
    const float* gsrc = state + blk_row0 * DDIM;
#pragma unroll
    for (int i = 0; i < 8; ++i) {
      int c = i * 256 + tid;                   // float4-chunk id 0..2047 (32 per row)
      int r = c >> 5, cc = c & 31;
      floatx4 v = *(const floatx4*)(gsrc + c * 4);
      short4v s;
      s[0] = (short)f2bf(v[0]); s[1] = (short)f2bf(v[1]);
      s[2] = (short)f2bf(v[2]); s[3] = (short)f2bf(v[3]);
      *(short4v*)(s_state + r * SD + cc * 4) = s;
    }
  }
  if (tid < MT) s_idx[tid] = idx[blk_row0 + tid];
  if (tid < 128) {                             // zero s_bufA cols 80..95 (64 rows x 2 chunks)
    int r = tid >> 1, cc = tid & 1;
    *(short8*)(s_bufA + r * SH + 80 + cc * 8) = zero8;
  }
  __syncthreads();

  const int g_lo = s_idx[0];
  const int g_hi = s_idx[MT - 1];              // idx sorted -> games in tile = [g_lo, g_hi]

  // ---- layer 1 (routed): h1 = relu(state @ W1[g]^T + b1[g]) ----
  for (int g = g_lo; g <= g_hi; ++g) {
    floatx4 acc[5];
#pragma unroll
    for (int ct = 0; ct < 5; ++ct) acc[ct] = (floatx4){0.f, 0.f, 0.f, 0.f};
    const unsigned short* w1g = wbf + W1O + g * (FDIM * DDIM);
#pragma unroll
    for (int ks = 0; ks < 4; ++ks) {
      int k0 = ks * 32 + quad * 8;
      short8 a = *(const short8*)(s_state + (rowbase + l16) * SD + k0);
      short8 bf[5];
#pragma unroll
      for (int ct = 0; ct < 5; ++ct)
        bf[ct] = *(const short8*)(w1g + (ct * 16 + l16) * DDIM + k0);
#pragma unroll
      for (int ct = 0; ct < 5; ++ct)
        acc[ct] = __builtin_amdgcn_mfma_f32_16x16x32_bf16(a, bf[ct], acc[ct], 0, 0, 0);
    }
#pragma unroll
    for (int ct = 0; ct < 5; ++ct) {
      int col = ct * 16 + l16;
      float bv = b1[g * FDIM + col];
#pragma unroll
      for (int r = 0; r < 4; ++r) {
        int row = rowbase + quad * 4 + r;
        if (s_idx[row] == g) {
          float v = fmaxf(acc[ct][r] + bv, 0.f);
          s_bufA[row * SH + col] = f2bf(v);
        }
      }
    }
  }
  // all waves done reading s_state as 'state' before anyone overwrites it with h2
  __syncthreads();

  unsigned short* s_h2 = s_state;              // reuse (stride SH)
  if (lane < 32) {                             // zero own rows' h2 pad cols 80..95
    int r = rowbase + (lane >> 1), cc = lane & 1;
    *(short8*)(s_h2 + r * SH + 80 + cc * 8) = zero8;
  }

  // ---- layers 2,3 (shared) ----
  mlp_layer(s_bufA, s_h2,  wbf + W2O, b2, rowbase, l16, quad);
  mlp_layer(s_h2,  s_bufA, wbf + W3O, b3, rowbase, l16, quad);

  // ---- layer 4 (routed heads): q = h3 @ W4[g]^T + b4[g], f32 out ----
  for (int g = g_lo; g <= g_hi; ++g) {
    floatx4 acc[2];
#pragma unroll
    for (int ct = 0; ct < 2; ++ct) acc[ct] = (floatx4){0.f, 0.f, 0.f, 0.f};
    const unsigned short* w4g = wbf + W4O + g * (32 * KP);
#pragma unroll
    for (int ks = 0; ks < 3; ++ks) {
      int k0 = ks * 32 + quad * 8;
      short8 a = *(const short8*)(s_bufA + (rowbase + l16) * SH + k0);
      short8 bf[2];
#pragma unroll
      for (int ct = 0; ct < 2; ++ct)
        bf[ct] = *(const short8*)(w4g + (ct * 16 + l16) * KP + k0);  // n,k pads are zeros
#pragma unroll
      for (int ct = 0; ct < 2; ++ct)
        acc[ct] = __builtin_amdgcn_mfma_f32_16x16x32_bf16(a, bf[ct], acc[ct], 0, 0, 0);
    }
#pragma unroll
    for (int ct = 0; ct < 2; ++ct) {
      int col = ct * 16 + l16;
      if (col < ADIM) {
        float bv = b4[g * ADIM + col];
#pragma unroll
        for (int r = 0; r < 4; ++r) {
          int row = rowbase + quad * 4 + r;
          if (s_idx[row] == g)
            out[(blk_row0 + row) * ADIM + col] = acc[ct][r] + bv;
        }
      }
    }
  }
}

extern "C" void kernel_launch(void* const* d_in, const int* in_sizes, int n_in,
                              void* d_out, int out_size, void* d_ws, size_t ws_size,
                              hipStream_t stream) {
  const float* state = (const float*)d_in[0];
  const int*   idx   = (const int*)d_in[1];
  const float* W1    = (const float*)d_in[2];
  const float* b1    = (const float*)d_in[3];
  const float* W2    = (const float*)d_in[4];
  const float* b2    = (const float*)d_in[5];
  const float* W3    = (const float*)d_in[6];
  const float* b3    = (const float*)d_in[7];
  const float* W4    = (const float*)d_in[8];
  const float* b4    = (const float*)d_in[9];
  float*       out   = (float*)d_out;
  unsigned short* wbf = (unsigned short*)d_ws;   // 243712 B used

  convert_weights<<<(WTOT + 255) / 256, 256, 0, stream>>>(W1, W2, W3, W4, wbf);
  gym_fused<<<B_TOT / MT, 256, 0, stream>>>(state, idx, wbf, b1, b2, b3, b4, out);
}